// Round 13
// baseline (221.739 us; speedup 1.0000x reference)
//
#include <hip/hip_runtime.h>
#include <hip/hip_bf16.h>

typedef unsigned short ushort_t;
typedef unsigned int uint_t;
typedef __attribute__((ext_vector_type(8))) short bf16x8;
typedef __attribute__((ext_vector_type(4))) float f32x4;

#define LEAKYC 0.3f
#define BNEPS 1e-5f

// sizes: B=8, CIN=128, LIN=2048, LOUT=4096, CMID=512, DM=256, NST=32

__device__ __forceinline__ ushort_t f2bf(float f){
    uint_t x = __float_as_uint(f);
    uint_t r = x + 0x7fffu + ((x >> 16) & 1u);
    return (ushort_t)(r >> 16);
}
__device__ __forceinline__ float bf2f(ushort_t u){
    return __uint_as_float(((uint_t)u) << 16);
}
__device__ __forceinline__ uint_t pack2(float a, float b){
    return (uint_t)f2bf(a) | ((uint_t)f2bf(b) << 16);
}
__device__ __forceinline__ float lrelu(float v){
    return (v >= 0.f) ? v : LEAKYC*v;
}

// ---------------------------------------------------------------------------
// Kernel 0: weight prep — fp32 w[d][i][o][tap] -> bf16 Wt[(d*2+tap)][o][i]
// ---------------------------------------------------------------------------
__global__ __launch_bounds__(256) void k_wprep(
    const float* __restrict__ w1, const float* __restrict__ w2,
    const float* __restrict__ w3, const float* __restrict__ w4,
    ushort_t* __restrict__ Wt)
{
    int g = blockIdx.x*256 + threadIdx.x;    // = i*256 + o*2 + t
    int i = g >> 8, o = (g >> 1) & 127, t = g & 1;
    int ob = (t*128 + o)*128 + i;
    Wt[ob]             = f2bf(w1[g]);
    Wt[2*16384 + ob]   = f2bf(w2[g]);
    Wt[4*16384 + ob]   = f2bf(w3[g]);
    Wt[6*16384 + ob]   = f2bf(w4[g]);
}

// ---------------------------------------------------------------------------
// Kernel 1: deconv via bf16 MFMA  (unchanged, verified round 11)
// ---------------------------------------------------------------------------
__global__ __launch_bounds__(256) void k_deconv(
    const float* __restrict__ x, const ushort_t* __restrict__ Wt,
    const float* __restrict__ b1, const float* __restrict__ b2,
    const float* __restrict__ b3, const float* __restrict__ b4,
    ushort_t* __restrict__ zT)
{
    __shared__ float xs[128*41];
    const int tx = threadIdx.x, lane = tx & 63;
    const int d  = tx >> 6;
    const int bb = blockIdx.x >> 6, lt = blockIdx.x & 63;
    const int l0 = lt*32;
    const float* xb = x + (size_t)bb*262144;

    for (int it = 0; it < 16; it++){
        int idx = it*256 + tx;
        int i = idx >> 5, lc = idx & 31;
        xs[i*41 + 4 + lc] = xb[i*2048 + l0 + lc];
    }
    for (int it = 0; it < 2; it++){
        int idx = it*256 + tx;
        int i = idx >> 2, dl = idx & 3;
        int l = l0 - 4 + dl;
        xs[i*41 + dl] = (l >= 0) ? xb[i*2048 + l] : 0.f;
    }
    __syncthreads();

    const int r = lane & 15, q = lane >> 4;
    const int S  = (d==0) ? 0 : (1 << (d-1));
    const int NT = (d==0) ? 4 : 2;
    const float* bd = (d==0) ? b1 : (d==1) ? b2 : (d==2) ? b3 : b4;
    const size_t zrowb = (size_t)bb*4096 + (size_t)lt*64;

    for (int tt = 0; tt < NT; tt++){
        const int ob   = (d==0) ? ((tt&1)*64) : tt*64;
        const int tapA = (d==0) ? (tt>>1) : 0;
        const int nseg = (d==0) ? 1 : 2;
        f32x4 acc[4][2] = {};
        for (int sg = 0; sg < nseg; sg++){
            const int tap = (d==0) ? tapA : sg;
            const int sh  = (sg==1) ? S : 0;
            const ushort_t* Arow = Wt + ((size_t)((d*2+tap)*128 + ob + r))*128 + q*8;
            const float* xcolb = xs + 4 + r - sh;
            #pragma unroll
            for (int kc = 0; kc < 4; kc++){
                uint4 a4[4];
                #pragma unroll
                for (int mi = 0; mi < 4; mi++)
                    a4[mi] = *(const uint4*)(Arow + mi*2048 + kc*32);
                const int kb = kc*32 + q*8;
                uint_t bfr[2][4];
                #pragma unroll
                for (int nj = 0; nj < 2; nj++){
                    const float* xc = xcolb + nj*16;
                    #pragma unroll
                    for (int kk = 0; kk < 4; kk++){
                        float e0 = xc[(kb + 2*kk)*41];
                        float e1 = xc[(kb + 2*kk + 1)*41];
                        bfr[nj][kk] = pack2(e0, e1);
                    }
                }
                #pragma unroll
                for (int mi = 0; mi < 4; mi++){
                    #pragma unroll
                    for (int nj = 0; nj < 2; nj++){
                        acc[mi][nj] = __builtin_amdgcn_mfma_f32_16x16x32_bf16(
                            *(const bf16x8*)&a4[mi], *(const bf16x8*)bfr[nj],
                            acc[mi][nj], 0, 0, 0);
                    }
                }
            }
        }
        const int podd = (d==0 && tapA==1) ? 1 : 0;
        #pragma unroll
        for (int mi = 0; mi < 4; mi++){
            const int oo = ob + mi*16 + q*4;
            const float4 bq = *(const float4*)(bd + oo);
            const int c = d*128 + oo;
            #pragma unroll
            for (int nj = 0; nj < 2; nj++){
                f32x4 v = acc[mi][nj];
                float z0 = v[0] + bq.x, z1 = v[1] + bq.y;
                float z2 = v[2] + bq.z, z3 = v[3] + bq.w;
                if (d > 0){
                    z0 = lrelu(z0); z1 = lrelu(z1);
                    z2 = lrelu(z2); z3 = lrelu(z3);
                }
                const int lcol = nj*16 + r;
                size_t row = zrowb + 2*lcol + podd;
                uint2 pk = { pack2(z0, z1), pack2(z2, z3) };
                *(uint2*)(zT + row*512 + c) = pk;
            }
        }
    }

    if (d > 0){
        #pragma unroll
        for (int rep = 0; rep < 8; rep++){
            int idx = rep*64 + lane;
            int li = idx >> 4, cg = (idx & 15)*8;
            float4 f0 = *(const float4*)(bd + cg);
            float4 f1 = *(const float4*)(bd + cg + 4);
            uint4 pkv = { pack2(lrelu(f0.x), lrelu(f0.y)),
                          pack2(lrelu(f0.z), lrelu(f0.w)),
                          pack2(lrelu(f1.x), lrelu(f1.y)),
                          pack2(lrelu(f1.z), lrelu(f1.w)) };
            size_t row = zrowb + 2*li + 1;
            *(uint4*)(zT + row*512 + d*128 + cg) = pkv;
        }
    }
}

// ---------------------------------------------------------------------------
// Kernel 1b: BN stats from zT (bf16)  (unchanged, verified)
// ---------------------------------------------------------------------------
__global__ __launch_bounds__(256) void k_stats(
    const ushort_t* __restrict__ zT, float* __restrict__ stats)
{
    const int tx = threadIdx.x;
    const int c = 2*tx;
    const ushort_t* base = zT + (size_t)blockIdx.x*128*512 + c;
    float s0=0.f, s1=0.f, q0=0.f, q1=0.f;
    for (int rr = 0; rr < 128; rr++){
        ushort2 v = *(const ushort2*)(base + (size_t)rr*512);
        float f0 = bf2f(v.x), f1 = bf2f(v.y);
        s0 += f0; s1 += f1;
        q0 += f0*f0; q1 += f1*f1;
    }
    atomicAdd(&stats[c],       s0);
    atomicAdd(&stats[c+1],     s1);
    atomicAdd(&stats[512+c],   q0);
    atomicAdd(&stats[512+c+1], q1);
}

// ---------------------------------------------------------------------------
// Kernel 2a: BN scale/shift  (unchanged, verified)
// ---------------------------------------------------------------------------
__global__ void k_bnstats(const float* __restrict__ stats,
                          const float* __restrict__ gamma, const float* __restrict__ beta,
                          float* __restrict__ scale, float* __restrict__ shift)
{
    int c = threadIdx.x;
    const float N = 32768.f;
    float mean = stats[c] / N;
    float var  = stats[512 + c] / N - mean*mean;
    var = fmaxf(var, 0.f);
    float sc = gamma[c & 127] * rsqrtf(var + BNEPS);
    scale[c] = sc;
    shift[c] = beta[c & 127] - mean * sc;
}

// ---------------------------------------------------------------------------
// Kernel 2b: fold BN into conv weights  (unchanged, verified)
// ---------------------------------------------------------------------------
__global__ __launch_bounds__(256) void k_fold(
    const float* __restrict__ cw, const float* __restrict__ cb,
    const float* __restrict__ scale, const float* __restrict__ shift,
    ushort_t* __restrict__ Wfbf, float* __restrict__ constb)
{
    __shared__ float red[256];
    int m = blockIdx.x;
    int tx = threadIdx.x;
    int c1 = tx, c2 = tx + 256;
    float wv1 = cw[m*512 + c1], wv2 = cw[m*512 + c2];
    Wfbf[m*512 + c1] = f2bf(wv1 * scale[c1]);
    Wfbf[m*512 + c2] = f2bf(wv2 * scale[c2]);
    red[tx] = wv1*shift[c1] + wv2*shift[c2];
    __syncthreads();
    for (int s = 128; s > 0; s >>= 1){
        if (tx < s) red[tx] += red[tx + s];
        __syncthreads();
    }
    if (tx == 0) constb[m] = cb[m] + red[0];
}

// ---------------------------------------------------------------------------
// Kernel 3: 1x1 conv GEMM via bf16 MFMA — now writes u as bf16 (u2)
// ---------------------------------------------------------------------------
__global__ __launch_bounds__(256) void k_conv(
    const ushort_t* __restrict__ zT, const ushort_t* __restrict__ Wfbf,
    const float* __restrict__ constb, ushort_t* __restrict__ u2)
{
    __shared__ ushort_t As[128*40];
    __shared__ ushort_t Bs[128*40];
    const int tx  = threadIdx.x;
    const int bid = blockIdx.x;
    const int pt = bid & 31, b = (bid >> 5) & 7, mt = bid >> 8;
    const int m0 = mt*128, pbase = pt*128;
    const int lane = tx & 63, wvid = tx >> 6;
    const int r = lane & 15, q = lane >> 4;
    const int wm = (wvid & 1)*64, wp = (wvid >> 1)*64;

    const int smm = tx >> 1;
    const int skk = (tx & 1) * 16;

    const ushort_t* gA = Wfbf + (m0 + smm)*512 + skk;
    const ushort_t* gB = zT + ((size_t)(b*4096 + pbase + smm))*512 + skk;

    f32x4 acc[4][4] = {};
    uint4 ra0, ra1, rb0, rb1;
    ra0 = *(const uint4*)(gA);     ra1 = *(const uint4*)(gA + 8);
    rb0 = *(const uint4*)(gB);     rb1 = *(const uint4*)(gB + 8);

    for (int ct = 0; ct < 16; ct++){
        __syncthreads();
        *(uint4*)(&As[smm*40 + skk])     = ra0;
        *(uint4*)(&As[smm*40 + skk + 8]) = ra1;
        *(uint4*)(&Bs[smm*40 + skk])     = rb0;
        *(uint4*)(&Bs[smm*40 + skk + 8]) = rb1;
        __syncthreads();
        if (ct < 15){
            const ushort_t* gA2 = gA + (ct+1)*32;
            const ushort_t* gB2 = gB + (ct+1)*32;
            ra0 = *(const uint4*)(gA2); ra1 = *(const uint4*)(gA2 + 8);
            rb0 = *(const uint4*)(gB2); rb1 = *(const uint4*)(gB2 + 8);
        }
        bf16x8 af[4], bfv[4];
        #pragma unroll
        for (int f = 0; f < 4; f++){
            af[f]  = *(const bf16x8*)(&As[(wm + f*16 + r)*40 + 8*q]);
            bfv[f] = *(const bf16x8*)(&Bs[(wp + f*16 + r)*40 + 8*q]);
        }
        #pragma unroll
        for (int i = 0; i < 4; i++){
            #pragma unroll
            for (int j = 0; j < 4; j++){
                acc[i][j] = __builtin_amdgcn_mfma_f32_16x16x32_bf16(af[i], bfv[j], acc[i][j], 0, 0, 0);
            }
        }
    }
    #pragma unroll
    for (int i = 0; i < 4; i++){
        #pragma unroll
        for (int t = 0; t < 4; t++){
            int m = m0 + wm + i*16 + 4*q + t;
            float cbv = constb[m];
            ushort_t* up = u2 + ((size_t)(b*256 + m))*4096 + pbase + wp + r;
            #pragma unroll
            for (int j = 0; j < 4; j++)
                up[j*16] = f2bf(acc[i][j][t] + cbv);
        }
    }
}

// ---------------------------------------------------------------------------
// Kernel 4 (fused ssmprep+matprep): per-h scan matrices + dA^64 carries.
//  Wm[h][j][tau]: j=2n -> Re(dA^(63-tau)), j=2n+1 -> Im
//  TVm[h][t][k]:  k<64: causal Toeplitz K[t-k] (+D diag); k>=64: V carry matrix
//  dATr/dATi[h*32+n] = dA^64  (for scan2)
// ---------------------------------------------------------------------------
__global__ __launch_bounds__(64) void k_matprep(
    const float* __restrict__ Are, const float* __restrict__ Aim,
    const float* __restrict__ logdt,
    const float* __restrict__ Cre, const float* __restrict__ Cim,
    const float* __restrict__ Dp,
    ushort_t* __restrict__ Wm, ushort_t* __restrict__ TVm,
    float* __restrict__ dATr, float* __restrict__ dATi)
{
    __shared__ float pr[32*65];
    __shared__ float pi[32*65];
    __shared__ float Ks[64];
    __shared__ float cfr_s[32], cfi_s[32];
    const int h = blockIdx.x, tx = threadIdx.x;
    if (tx < 32){
        const int g = h*32 + tx;
        const float ar0 = Are[g], ai0 = Aim[g];
        const float dt = expf(logdt[h]);
        const float ea = expf(dt*ar0);
        const float ar = ea * cosf(dt*ai0);   // dA
        const float ai = ea * sinf(dt*ai0);
        const float nr = ar - 1.f, nimm = ai;
        const float den = ar0*ar0 + ai0*ai0;
        const float dBr = (nr*ar0 + nimm*ai0) / den;
        const float dBi = (nimm*ar0 - nr*ai0) / den;
        cfr_s[tx] = 2.f*(Cre[g]*dBr - Cim[g]*dBi);
        cfi_s[tx] = 2.f*(Cre[g]*dBi + Cim[g]*dBr);
        float xr = 1.f, xi = 0.f;
        for (int p = 0; p < 65; p++){
            pr[tx*65 + p] = xr; pi[tx*65 + p] = xi;
            float nx = xr*ar - xi*ai;
            float ny = xr*ai + xi*ar;
            xr = nx; xi = ny;
        }
        dATr[g] = pr[tx*65 + 64];
        dATi[g] = pi[tx*65 + 64];
    }
    __syncthreads();
    {
        float s = 0.f;
        for (int n = 0; n < 32; n++)
            s += cfr_s[n]*pr[n*65 + tx] - cfi_s[n]*pi[n*65 + tx];
        Ks[tx] = s;
    }
    __syncthreads();
    const float Dh = Dp[h];
    {   // Wm row j = tx
        const int n = tx >> 1;
        const int isim = tx & 1;
        ushort_t* wrow = Wm + (size_t)h*4096 + tx*64;
        for (int tau = 0; tau < 64; tau++){
            float v = isim ? pi[n*65 + 63 - tau] : pr[n*65 + 63 - tau];
            wrow[tau] = f2bf(v);
        }
    }
    {   // TVm row t = tx
        ushort_t* trow = TVm + (size_t)h*8192 + tx*128;
        for (int k = 0; k < 64; k++){
            float v = (tx >= k) ? (Ks[tx - k] + ((tx == k) ? Dh : 0.f)) : 0.f;
            trow[k] = f2bf(v);
        }
        for (int j = 0; j < 64; j++){
            const int n = j >> 1;
            const float cfr = cfr_s[n], cfi = cfi_s[n];
            const float P = pr[n*65 + tx + 1], Q = pi[n*65 + tx + 1];
            float v = (j & 1) ? -(cfr*Q + cfi*P) : (cfr*P - cfi*Q);
            trow[64 + j] = f2bf(v);
        }
    }
}

// ---------------------------------------------------------------------------
// Kernel 5: chunk end-states via MFMA (u2 bf16 input)
// ---------------------------------------------------------------------------
__global__ __launch_bounds__(256) void k_sgemm1(
    const ushort_t* __restrict__ u2, const ushort_t* __restrict__ Wm,
    ushort_t* __restrict__ S)
{
    __shared__ ushort_t Ul[256*72];
    __shared__ ushort_t Wl[64*72];
    const int tx = threadIdx.x;
    const int h = blockIdx.x >> 1, bh = (blockIdx.x & 1)*4;
    for (int rr = 0; rr < 16; rr++){
        int idx = rr*256 + tx;
        int j = idx >> 6, col = idx & 63;
        Wl[j*72 + col] = Wm[(size_t)h*4096 + idx];
    }
    for (int rr = 0; rr < 16; rr++){
        int idx = rr*256 + tx;
        int row = idx >> 4, fi = idx & 15;
        int bb = row >> 6, cc = row & 63;
        const ushort_t* up = u2 + ((size_t)((bh+bb)*256 + h))*4096 + cc*64 + fi*4;
        *(uint2*)&Ul[row*72 + fi*4] = *(const uint2*)up;
    }
    __syncthreads();
    const int lane = tx & 63, w = tx >> 6;
    const int r = lane & 15, q = lane >> 4;
    const int wm = w*64;
    f32x4 acc[4][4] = {};
    #pragma unroll
    for (int kc = 0; kc < 2; kc++){
        bf16x8 af[4], bv[4];
        #pragma unroll
        for (int mi = 0; mi < 4; mi++)
            af[mi] = *(const bf16x8*)&Ul[(wm + mi*16 + r)*72 + kc*32 + q*8];
        #pragma unroll
        for (int nj = 0; nj < 4; nj++)
            bv[nj] = *(const bf16x8*)&Wl[(nj*16 + r)*72 + kc*32 + q*8];
        #pragma unroll
        for (int mi = 0; mi < 4; mi++){
            #pragma unroll
            for (int nj = 0; nj < 4; nj++){
                acc[mi][nj] = __builtin_amdgcn_mfma_f32_16x16x32_bf16(af[mi], bv[nj], acc[mi][nj], 0, 0, 0);
            }
        }
    }
    #pragma unroll
    for (int mi = 0; mi < 4; mi++){
        #pragma unroll
        for (int tt = 0; tt < 4; tt++){
            int row = wm + mi*16 + 4*q + tt;
            int bb = row >> 6, cc = row & 63;
            ushort_t* sp = S + ((size_t)((bh+bb)*256 + h))*4096 + cc*64;
            #pragma unroll
            for (int nj = 0; nj < 4; nj++)
                sp[nj*16 + r] = f2bf(acc[mi][nj][tt]);
        }
    }
}

// ---------------------------------------------------------------------------
// Kernel 6: scan pass 2 — sequential carry combine over chunks (bf16 S)
// ---------------------------------------------------------------------------
__global__ __launch_bounds__(256) void k_scan2(
    ushort_t* __restrict__ S, const float* __restrict__ dATr_, const float* __restrict__ dATi_)
{
    int g = blockIdx.x*256 + threadIdx.x;
    int n = g & 31, h = (g >> 5) & 255, b = g >> 13;
    float ar = dATr_[h*32 + n], ai = dATi_[h*32 + n];
    float cr = 0.f, ci = 0.f;
    uint_t* p = (uint_t*)S + (size_t)(b*256 + h)*2048 + n;
    for (int c = 0; c < 64; c++){
        uint_t t = *p;
        float tr = bf2f((ushort_t)(t & 0xffff));
        float ti = bf2f((ushort_t)(t >> 16));
        *p = pack2(cr, ci);
        float ncr = fmaf(ar, cr, tr);
        ncr = fmaf(-ai, ci, ncr);
        float nci = fmaf(ai, cr, ti);
        nci = fmaf(ar, ci, nci);
        cr = ncr; ci = nci;
        p += 32;
    }
}

// ---------------------------------------------------------------------------
// Kernel 7: outputs via MFMA: Y = U·T^T + Sin·V^T  (u2 bf16 input)
// ---------------------------------------------------------------------------
__global__ __launch_bounds__(256) void k_sgemm2(
    const ushort_t* __restrict__ u2, const ushort_t* __restrict__ S,
    const ushort_t* __restrict__ TVm, float* __restrict__ out)
{
    __shared__ ushort_t Al[256*72];
    __shared__ ushort_t Bl[64*136];
    const int tx = threadIdx.x;
    const int h = blockIdx.x >> 1, bh = (blockIdx.x & 1)*4;
    for (int rr = 0; rr < 32; rr++){
        int idx = rr*256 + tx;
        int t = idx >> 7, k = idx & 127;
        Bl[t*136 + k] = TVm[(size_t)h*8192 + idx];
    }
    const int lane = tx & 63, w = tx >> 6;
    const int r = lane & 15, q = lane >> 4;
    const int wm = w*64;
    f32x4 acc[4][4] = {};
    #pragma unroll
    for (int half = 0; half < 2; half++){
        __syncthreads();
        const ushort_t* src = (half == 0) ? u2 : S;
        for (int rr = 0; rr < 16; rr++){
            int idx = rr*256 + tx;
            int row = idx >> 4, fi = idx & 15;
            int bb = row >> 6, cc = row & 63;
            const ushort_t* sp = src + ((size_t)((bh+bb)*256 + h))*4096 + cc*64 + fi*4;
            *(uint2*)&Al[row*72 + fi*4] = *(const uint2*)sp;
        }
        __syncthreads();
        #pragma unroll
        for (int kc = 0; kc < 2; kc++){
            bf16x8 af[4], bv[4];
            #pragma unroll
            for (int mi = 0; mi < 4; mi++)
                af[mi] = *(const bf16x8*)&Al[(wm + mi*16 + r)*72 + kc*32 + q*8];
            #pragma unroll
            for (int nj = 0; nj < 4; nj++)
                bv[nj] = *(const bf16x8*)&Bl[(nj*16 + r)*136 + half*64 + kc*32 + q*8];
            #pragma unroll
            for (int mi = 0; mi < 4; mi++){
                #pragma unroll
                for (int nj = 0; nj < 4; nj++){
                    acc[mi][nj] = __builtin_amdgcn_mfma_f32_16x16x32_bf16(af[mi], bv[nj], acc[mi][nj], 0, 0, 0);
                }
            }
        }
    }
    #pragma unroll
    for (int mi = 0; mi < 4; mi++){
        #pragma unroll
        for (int tt = 0; tt < 4; tt++){
            int row = wm + mi*16 + 4*q + tt;
            int bb = row >> 6, cc = row & 63;
            float* op = out + ((size_t)((bh+bb)*256 + h))*4096 + cc*64;
            #pragma unroll
            for (int nj = 0; nj < 4; nj++)
                op[nj*16 + r] = acc[mi][nj][tt];
        }
    }
}

// ---------------------------------------------------------------------------
extern "C" void kernel_launch(void* const* d_in, const int* in_sizes, int n_in,
                              void* d_out, int out_size, void* d_ws, size_t ws_size,
                              hipStream_t stream)
{
    (void)in_sizes; (void)n_in; (void)out_size; (void)ws_size;
    const float* x     = (const float*)d_in[0];
    const float* w1    = (const float*)d_in[1];
    const float* b1    = (const float*)d_in[2];
    const float* w2    = (const float*)d_in[3];
    const float* b2    = (const float*)d_in[4];
    const float* w3    = (const float*)d_in[5];
    const float* b3    = (const float*)d_in[6];
    const float* w4    = (const float*)d_in[7];
    const float* b4    = (const float*)d_in[8];
    const float* gamma = (const float*)d_in[9];
    const float* beta  = (const float*)d_in[10];
    const float* cw    = (const float*)d_in[11];
    const float* cb    = (const float*)d_in[12];
    const float* Are   = (const float*)d_in[13];
    const float* Aim   = (const float*)d_in[14];
    const float* logdt = (const float*)d_in[15];
    const float* Cre   = (const float*)d_in[16];
    const float* Cim   = (const float*)d_in[17];
    const float* Dp    = (const float*)d_in[18];
    float* out = (float*)d_out;

    char* ws = (char*)d_ws;
    ushort_t* zT = (ushort_t*)ws;                 // 32 MB, dead after k_conv
    ushort_t* u2 = (ushort_t*)(ws + 33554432);    // 16 MB bf16 u
    // zT region reuse (written AFTER k_conv completes):
    ushort_t* S   = (ushort_t*)ws;                // 16 MB bf16 chunk states / carries
    ushort_t* Wm  = (ushort_t*)(ws + 16777216);   // 2 MB
    ushort_t* TVm = (ushort_t*)(ws + 18874368);   // 4 MB
    char* mscB   = ws + 67108864;
    float* stats   = (float*)(mscB + 0);
    float* scale   = (float*)(mscB + 4096);
    float* shift   = (float*)(mscB + 6144);
    float* constb  = (float*)(mscB + 8192);
    ushort_t* Wfbf = (ushort_t*)(mscB + 9216);    // 262144 B
    float* ssm     = (float*)(mscB + 271360);     // dAT storage
    ushort_t* Wt   = (ushort_t*)(mscB + 467968);  // 262144 B
    float* dATr = ssm + 16384;
    float* dATi = ssm + 24576;

    hipMemsetAsync(stats, 0, 1024*sizeof(float), stream);
    k_wprep<<<128, 256, 0, stream>>>(w1, w2, w3, w4, Wt);
    k_deconv<<<512, 256, 0, stream>>>(x, Wt, b1, b2, b3, b4, zT);
    k_stats<<<256, 256, 0, stream>>>(zT, stats);
    k_bnstats<<<1, 512, 0, stream>>>(stats, gamma, beta, scale, shift);
    k_fold<<<256, 256, 0, stream>>>(cw, cb, scale, shift, Wfbf, constb);
    k_conv<<<512, 256, 0, stream>>>(zT, Wfbf, constb, u2);
    k_matprep<<<256, 64, 0, stream>>>(Are, Aim, logdt, Cre, Cim, Dp, Wm, TVm, dATr, dATi);
    k_sgemm1<<<512, 256, 0, stream>>>(u2, Wm, S);
    k_scan2<<<256, 256, 0, stream>>>(S, dATr, dATi);
    k_sgemm2<<<512, 256, 0, stream>>>(u2, S, TVm, out);
}